// Round 2
// baseline (6745.389 us; speedup 1.0000x reference)
//
#include <hip/hip_runtime.h>
#include <hip/hip_bf16.h>

// GRU sequence: B=64, T=512, LATENT=512, HIDDEN=1024.
// Inputs/outputs are FP32 (reference is jnp.float32). Compute lowered to bf16
// MFMA with fp32 accumulation (threshold 1.72e-2 absolute permits this).
//
//   K0: convert W_ih, W_hh fp32 -> bf16 (once per launch, into ws)
//   K1: x_proj = z @ W_ih^T + b_ih   (32768x3072x512 bf16 MFMA) -> XP (bf16, ws)
//   K2 (x512): gh = h @ W_hh^T + b_hh, gates, h_new; fused per timestep.
//       h carried in fp32 (precision) + bf16 shadow (MFMA operand), double-buffered.

#define B_   64
#define T_   512
#define LAT_ 512
#define HID_ 1024
#define G3_  3072

typedef __bf16  bf8  __attribute__((ext_vector_type(8)));
typedef float   f4   __attribute__((ext_vector_type(4)));
typedef short   s8v  __attribute__((ext_vector_type(8)));
typedef short   s4v  __attribute__((ext_vector_type(4)));

__device__ __forceinline__ bf8 ldb8(const short* p) {
    s8v v = *(const s8v*)p;
    return __builtin_bit_cast(bf8, v);
}
__device__ __forceinline__ float b2f(short s) {
    return __bfloat162float(*(__hip_bfloat16*)&s);
}
__device__ __forceinline__ short f2b(float f) {
    __hip_bfloat16 h = __float2bfloat16(f);
    return *(short*)&h;
}

// ---------------------------------------------------------------------------
// K0: fp32 -> bf16 elementwise (n multiple of 1024; each thread does 4)
// ---------------------------------------------------------------------------
__global__ __launch_bounds__(256) void cvt_f2b_kernel(
    const float* __restrict__ in, short* __restrict__ out, int n)
{
    int i = (blockIdx.x * 256 + threadIdx.x) * 4;
    if (i + 3 < n) {
        f4 v = *(const f4*)(in + i);
        s4v r;
        r.x = f2b(v.x); r.y = f2b(v.y); r.z = f2b(v.z); r.w = f2b(v.w);
        *(s4v*)(out + i) = r;
    }
}

// ---------------------------------------------------------------------------
// K1: XP[r,g] = sum_k Z[r,k]*Wih[g,k] + bih[g];  r in [0,32768), g in [0,3072)
// 128x128 tile, BK=32, 256 threads (2x2 waves of 64x64), mfma 16x16x32 bf16.
// Z is fp32: converted to bf16 during LDS staging. Wih pre-converted (bf16).
// ---------------------------------------------------------------------------
__global__ __launch_bounds__(256) void xproj_kernel(
    const float* __restrict__ Z,     // (32768, 512) fp32
    const short* __restrict__ Wih,   // (3072, 512) bf16
    const float* __restrict__ bih,   // (3072) fp32
    short* __restrict__ XP)          // (32768, 3072) bf16
{
    __shared__ short As[128 * 32];
    __shared__ short Bs[128 * 32];

    const int tid  = threadIdx.x;
    const int lane = tid & 63;
    const int wid  = tid >> 6;
    const int wm   = wid & 1;
    const int wn   = wid >> 1;
    const int lrow = lane & 15;
    const int quad = lane >> 4;

    const long arow0 = (long)blockIdx.y * 128;   // M tile base
    const long brow0 = (long)blockIdx.x * 128;   // N tile base

    f4 acc[4][4];
    const f4 zf = {0.f, 0.f, 0.f, 0.f};
#pragma unroll
    for (int i = 0; i < 4; i++)
#pragma unroll
        for (int j = 0; j < 4; j++) acc[i][j] = zf;

    for (int k0 = 0; k0 < LAT_; k0 += 32) {
        // A tile: 128x32 fp32 -> bf16. 1024 chunks of 4 floats; 4 per thread.
#pragma unroll
        for (int i = 0; i < 4; i++) {
            int c   = tid + 256 * i;
            int row = c >> 3;            // 0..127
            int kc  = (c & 7) * 4;       // 0..28
            f4 v = *(const f4*)(Z + (arow0 + row) * LAT_ + k0 + kc);
            s4v r;
            r.x = f2b(v.x); r.y = f2b(v.y); r.z = f2b(v.z); r.w = f2b(v.w);
            *(s4v*)(As + row * 32 + kc) = r;
        }
        // B tile: 128x32 bf16. 512 chunks of 8; 2 per thread.
#pragma unroll
        for (int i = 0; i < 2; i++) {
            int c   = tid + 256 * i;
            int row = c >> 2;
            int kc  = (c & 3) * 8;
            *(s8v*)(Bs + row * 32 + kc) = *(const s8v*)(Wih + (brow0 + row) * LAT_ + k0 + kc);
        }
        __syncthreads();

        bf8 af[4], bfr[4];
#pragma unroll
        for (int mf = 0; mf < 4; mf++)
            af[mf] = ldb8(As + (wm * 64 + mf * 16 + lrow) * 32 + quad * 8);
#pragma unroll
        for (int nf = 0; nf < 4; nf++)
            bfr[nf] = ldb8(Bs + (wn * 64 + nf * 16 + lrow) * 32 + quad * 8);

#pragma unroll
        for (int mf = 0; mf < 4; mf++)
#pragma unroll
            for (int nf = 0; nf < 4; nf++)
                acc[mf][nf] = __builtin_amdgcn_mfma_f32_16x16x32_bf16(
                    af[mf], bfr[nf], acc[mf][nf], 0, 0, 0);
        __syncthreads();
    }

    // epilogue: C/D layout col = lane&15, row = quad*4 + reg
#pragma unroll
    for (int nf = 0; nf < 4; nf++) {
        int gc = (int)brow0 + wn * 64 + nf * 16 + lrow;
        float bias = bih[gc];
#pragma unroll
        for (int mf = 0; mf < 4; mf++) {
#pragma unroll
            for (int r = 0; r < 4; r++) {
                long gr = arow0 + wm * 64 + mf * 16 + quad * 4 + r;
                XP[gr * G3_ + gc] = f2b(acc[mf][nf][r] + bias);
            }
        }
    }
}

// ---------------------------------------------------------------------------
// K2: one timestep. 64 blocks x 256 threads. Block owns 16 h-columns (3 gates).
// 4 waves split K=1024 into 4x256; LDS reduce; fused gate math. Output fp32.
// ---------------------------------------------------------------------------
__global__ __launch_bounds__(256) void step_kernel(
    const short* __restrict__ Hbf,   // (64,1024) bf16 h_old
    const float* __restrict__ Hfp,   // (64,1024) fp32 h_old
    const short* __restrict__ Whh,   // (3072,1024) bf16
    const short* __restrict__ XP,    // (32768,3072) bf16
    const float* __restrict__ bhh,   // (3072) fp32
    short* __restrict__ HbfN,
    float* __restrict__ HfpN,
    float* __restrict__ Out,         // (64,512,1024) fp32
    int t)
{
    __shared__ float red[4 * 64 * 48];   // 48 KB

    const int tid  = threadIdx.x;
    const int lane = tid & 63;
    const int w    = tid >> 6;
    const int lrow = lane & 15;
    const int quad = lane >> 4;
    const int c0   = blockIdx.x * 16;

    f4 acc[4][3];
    const f4 zf = {0.f, 0.f, 0.f, 0.f};
#pragma unroll
    for (int i = 0; i < 4; i++)
#pragma unroll
        for (int g = 0; g < 3; g++) acc[i][g] = zf;

    const int kbase = w * 256;
    for (int kk = 0; kk < 256; kk += 32) {
        int k = kbase + kk + quad * 8;
        bf8 a[4];
#pragma unroll
        for (int mf = 0; mf < 4; mf++)
            a[mf] = ldb8(Hbf + (mf * 16 + lrow) * HID_ + k);
#pragma unroll
        for (int g = 0; g < 3; g++) {
            bf8 b = ldb8(Whh + (g * HID_ + c0 + lrow) * HID_ + k);
#pragma unroll
            for (int mf = 0; mf < 4; mf++)
                acc[mf][g] = __builtin_amdgcn_mfma_f32_16x16x32_bf16(
                    a[mf], b, acc[mf][g], 0, 0, 0);
        }
    }

    // partials -> LDS.  m = mf*16 + quad*4 + r, col = g*16 + lrow
#pragma unroll
    for (int mf = 0; mf < 4; mf++)
#pragma unroll
        for (int g = 0; g < 3; g++)
#pragma unroll
            for (int r = 0; r < 4; r++)
                red[(w * 64 + mf * 16 + quad * 4 + r) * 48 + g * 16 + lrow] = acc[mf][g][r];
    __syncthreads();

    // final reduction + gates: 1024 elements (m in [0,64), j in [0,16))
    for (int e = tid; e < 1024; e += 256) {
        int m = e >> 4;
        int j = e & 15;
        float ghr = 0.f, ghz = 0.f, ghn = 0.f;
#pragma unroll
        for (int ww = 0; ww < 4; ww++) {
            const float* rr = red + (ww * 64 + m) * 48;
            ghr += rr[j];
            ghz += rr[16 + j];
            ghn += rr[32 + j];
        }
        int col = c0 + j;
        ghr += bhh[col];
        ghz += bhh[HID_ + col];
        ghn += bhh[2 * HID_ + col];

        const short* xrow = XP + (long)(m * T_ + t) * G3_;
        float xr = b2f(xrow[col]);
        float xz = b2f(xrow[HID_ + col]);
        float xn = b2f(xrow[2 * HID_ + col]);

        float r = 1.f / (1.f + __expf(-(xr + ghr)));
        float u = 1.f / (1.f + __expf(-(xz + ghz)));
        float n = tanhf(xn + r * ghn);
        float hold = Hfp[m * HID_ + col];
        float hnew = (1.f - u) * n + u * hold;

        HfpN[m * HID_ + col] = hnew;
        HbfN[m * HID_ + col] = f2b(hnew);
        Out[((long)m * T_ + t) * HID_ + col] = hnew;
    }
}

__global__ void init_h(float* hfp, short* hbf) {
    int i = blockIdx.x * 256 + threadIdx.x;   // 65536 elements
    hfp[i] = 0.f;
    hbf[i] = 0;
}

extern "C" void kernel_launch(void* const* d_in, const int* in_sizes, int n_in,
                              void* d_out, int out_size, void* d_ws, size_t ws_size,
                              hipStream_t stream) {
    const float* Z   = (const float*)d_in[0];   // (64,512,512)
    const float* Wih = (const float*)d_in[1];   // (3072,512)
    const float* Whh = (const float*)d_in[2];   // (3072,1024)
    const float* bih = (const float*)d_in[3];   // (3072)
    const float* bhh = (const float*)d_in[4];   // (3072)
    float* out = (float*)d_out;                 // (64,512,1024) fp32

    char* ws = (char*)d_ws;
    size_t off = 0;
    short* XP    = (short*)(ws + off); off += (size_t)B_ * T_ * G3_ * 2;   // 201.3 MB
    short* Wihbf = (short*)(ws + off); off += (size_t)G3_ * LAT_ * 2;      // 3.1 MB
    short* Whhbf = (short*)(ws + off); off += (size_t)G3_ * HID_ * 2;      // 6.3 MB
    float* hfp0  = (float*)(ws + off); off += (size_t)B_ * HID_ * 4;
    float* hfp1  = (float*)(ws + off); off += (size_t)B_ * HID_ * 4;
    short* hbf0  = (short*)(ws + off); off += (size_t)B_ * HID_ * 2;
    short* hbf1  = (short*)(ws + off); off += (size_t)B_ * HID_ * 2;

    // K0: weight conversion
    cvt_f2b_kernel<<<(G3_ * LAT_) / 1024, 256, 0, stream>>>(Wih, Wihbf, G3_ * LAT_);
    cvt_f2b_kernel<<<(G3_ * HID_) / 1024, 256, 0, stream>>>(Whh, Whhbf, G3_ * HID_);

    // K1: x_proj GEMM. grid (N tiles = 24, M tiles = 256)
    xproj_kernel<<<dim3(24, 256), 256, 0, stream>>>(Z, Wihbf, bih, XP);

    // h0 = 0
    init_h<<<(B_ * HID_) / 256, 256, 0, stream>>>(hfp0, hbf0);

    // K2: sequential recurrence, double-buffered h
    for (int t = 0; t < T_; t++) {
        float* hf_cur = (t & 1) ? hfp1 : hfp0;
        float* hf_nxt = (t & 1) ? hfp0 : hfp1;
        short* hb_cur = (t & 1) ? hbf1 : hbf0;
        short* hb_nxt = (t & 1) ? hbf0 : hbf1;
        step_kernel<<<64, 256, 0, stream>>>(hb_cur, hf_cur, Whhbf, XP, bhh,
                                            hb_nxt, hf_nxt, out, t);
    }
}